// Round 1
// baseline (1020.130 us; speedup 1.0000x reference)
//
#include <hip/hip_runtime.h>

// AttentionFusion on MI355X (gfx950).
// B=32, C=1024, HW=1024. All GEMMs are 1024x1024x1024, bf16 MFMA, fp32 acc.
//
// Pipeline per batch b (all operands K-contiguous "B^T" GEMMs):
//   Xt[s][c] = bf16(shape_map[b][c][s])   (transpose+convert)
//   Yt[s][c] = bf16(img_map[b][c][s])
//   Q[o][s]  = tanh(Wq[o][c] . Xt[s][c] + bq[o])        A=Wq,  B=Xt,  bias-m
//   K2[d][s] = tanh(Wk[d][c] . Yt[s][c] + bk[d])        A=Wk,  B=Yt,  bias-m
//   Vt[s][d] = tanh(Yt[s][c] . Wv[d][c] + bv[d])        A=Yt,  B=Wv,  bias-n
//   S[c][d]  = (1/32) Q[c][s] . K2[d][s]                fp32 out
//   Wsm[c][d]= softmax_row(S)                           bf16
//   NVt[s][c]= Vt[s][d] . Wsm[c][d]
//   out[o][s]= Wc[o][c] . NVt[s][c] + bc[o] + shape_map[b][o][s]  fp32 out

typedef __bf16 bf16x8 __attribute__((ext_vector_type(8)));
typedef float floatx4 __attribute__((ext_vector_type(4)));

__device__ __forceinline__ unsigned short f2bf(float f) {
  union { float f; unsigned int u; } c; c.f = f;
  unsigned int u = c.u;
  u += 0x7fffu + ((u >> 16) & 1u);   // RNE to bf16
  return (unsigned short)(u >> 16);
}

__device__ __forceinline__ float tanh_fast(float x) {
  x = fminf(15.0f, fmaxf(-15.0f, x));   // keep __expf finite
  float t = __expf(2.0f * x);
  return (t - 1.0f) / (t + 1.0f);
}

// ---------------------------------------------------------------------------
// Generic 1024^3 bf16 GEMM, C[m][n] = epi( scale * sum_k A[m][k]*B[n][k] )
// m97 structure: 128x128 tile, BK=32, 256 threads (4 waves, 2x2 of 64x64),
// global_load_lds width-16 staging, 16x16x32 bf16 MFMA.
// ---------------------------------------------------------------------------
template<int OUT_F32, int BIAS_MODE /*0 none,1 along m,2 along n*/,
         int TANH_ON, int RESID_ON>
__global__ __launch_bounds__(256, 2)
void gemm_bt(const unsigned short* __restrict__ A,
             const unsigned short* __restrict__ B,
             void* __restrict__ Cv,
             const float* __restrict__ bias,
             const float* __restrict__ resid,
             float scale,
             size_t sA, size_t sB, size_t sC, size_t sR)
{
  constexpr int K = 1024;
  const unsigned short* Ab = A + blockIdx.z * sA;
  const unsigned short* Bb = B + blockIdx.z * sB;

  __shared__ unsigned short lA[128 * 32];
  __shared__ unsigned short lB[128 * 32];

  const int tid  = threadIdx.x;
  const int w    = tid >> 6;
  const int lane = tid & 63;
  const int quad = lane >> 4;
  const int lm   = lane & 15;
  const int wm   = (w >> 1) * 64;
  const int wn   = (w & 1) * 64;
  const int m0 = blockIdx.y * 128, n0 = blockIdx.x * 128;

  // staging: lane covers 16B at (row = lane/4, col8 = (lane%4)*8)
  const int srow = lane >> 2;
  const int scol = (lane & 3) * 8;

  floatx4 acc[4][4];
#pragma unroll
  for (int i = 0; i < 4; ++i)
#pragma unroll
    for (int j = 0; j < 4; ++j)
      acc[i][j] = (floatx4)(0.0f);

  const unsigned short* gA0 = Ab + (size_t)(m0 + srow) * K + scol;
  const unsigned short* gB0 = Bb + (size_t)(n0 + srow) * K + scol;

  for (int k0 = 0; k0 < K; k0 += 32) {
    // each wave stages chunks q=w*2, w*2+1 of both tiles (1KB per issue,
    // HW scatters wave-uniform LDS base + lane*16)
#pragma unroll
    for (int i = 0; i < 2; ++i) {
      const int q = w * 2 + i;
      __builtin_amdgcn_global_load_lds(
          (__attribute__((address_space(1))) void*)(gA0 + (size_t)q * 16 * K + k0),
          (__attribute__((address_space(3))) void*)(&lA[q * 512]), 16, 0, 0);
      __builtin_amdgcn_global_load_lds(
          (__attribute__((address_space(1))) void*)(gB0 + (size_t)q * 16 * K + k0),
          (__attribute__((address_space(3))) void*)(&lB[q * 512]), 16, 0, 0);
    }
    __syncthreads();   // drains vmcnt(0) before barrier (verified semantics)

    bf16x8 af[4], bfv[4];
#pragma unroll
    for (int i = 0; i < 4; ++i)
      af[i] = *(const bf16x8*)(&lA[(wm + 16 * i + lm) * 32 + quad * 8]);
#pragma unroll
    for (int j = 0; j < 4; ++j)
      bfv[j] = *(const bf16x8*)(&lB[(wn + 16 * j + lm) * 32 + quad * 8]);

#pragma unroll
    for (int i = 0; i < 4; ++i)
#pragma unroll
      for (int j = 0; j < 4; ++j)
        acc[i][j] = __builtin_amdgcn_mfma_f32_16x16x32_bf16(
            af[i], bfv[j], acc[i][j], 0, 0, 0);

    __syncthreads();   // protect LDS from next iteration's staging
  }

  float* Cf = (float*)Cv + blockIdx.z * sC;
  unsigned short* Cb = (unsigned short*)Cv + blockIdx.z * sC;
  const float* rp = RESID_ON ? (resid + blockIdx.z * sR) : (const float*)0;

  // C/D mapping (verified m89/m91): n = lane&15, m = quad*4 + reg
#pragma unroll
  for (int i = 0; i < 4; ++i) {
    const int mbase = m0 + wm + 16 * i + quad * 4;
#pragma unroll
    for (int j = 0; j < 4; ++j) {
      const int n = n0 + wn + 16 * j + lm;
#pragma unroll
      for (int r = 0; r < 4; ++r) {
        const int m = mbase + r;
        float val = acc[i][j][r] * scale;
        if (BIAS_MODE == 1) val += bias[m];
        if (BIAS_MODE == 2) val += bias[n];
        if (TANH_ON) val = tanh_fast(val);
        if (RESID_ON) val += rp[(size_t)m * 1024 + n];
        if (OUT_F32) Cf[(size_t)m * 1024 + n] = val;
        else         Cb[(size_t)m * 1024 + n] = f2bf(val);
      }
    }
  }
}

// ---------------------------------------------------------------------------
// Transpose 1024x1024 fp32 -> bf16 (out[s][c] = in[c][s])
// ---------------------------------------------------------------------------
__global__ __launch_bounds__(256)
void transpose_cvt(const float* __restrict__ in, unsigned short* __restrict__ out,
                   size_t sIn, size_t sOut)
{
  __shared__ float tile[32][33];
  in  += blockIdx.z * sIn;
  out += blockIdx.z * sOut;
  const int x  = blockIdx.x * 32 + threadIdx.x;
  const int y0 = blockIdx.y * 32;
#pragma unroll
  for (int k = 0; k < 32; k += 8)
    tile[threadIdx.y + k][threadIdx.x] =
        in[(size_t)(y0 + threadIdx.y + k) * 1024 + x];
  __syncthreads();
  const int xo  = blockIdx.y * 32 + threadIdx.x;
  const int yo0 = blockIdx.x * 32;
#pragma unroll
  for (int k = 0; k < 32; k += 8)
    out[(size_t)(yo0 + threadIdx.y + k) * 1024 + xo] =
        f2bf(tile[threadIdx.x][threadIdx.y + k]);
}

// ---------------------------------------------------------------------------
// Row softmax: 1024 fp32 scores -> 1024 bf16 weights, one block per row
// ---------------------------------------------------------------------------
__global__ __launch_bounds__(256)
void softmax_rows(const float* __restrict__ S, unsigned short* __restrict__ W,
                  size_t sS, size_t sW)
{
  const float* s = S + blockIdx.y * sS + (size_t)blockIdx.x * 1024;
  unsigned short* w = W + blockIdx.y * sW + (size_t)blockIdx.x * 1024;
  const int t = threadIdx.x;
  float4 v = ((const float4*)s)[t];
  float mx = fmaxf(fmaxf(v.x, v.y), fmaxf(v.z, v.w));
#pragma unroll
  for (int off = 32; off > 0; off >>= 1)
    mx = fmaxf(mx, __shfl_xor(mx, off));
  __shared__ float redm[4], reds[4];
  const int lane = t & 63, wv = t >> 6;
  if (lane == 0) redm[wv] = mx;
  __syncthreads();
  mx = fmaxf(fmaxf(redm[0], redm[1]), fmaxf(redm[2], redm[3]));
  float e0 = __expf(v.x - mx), e1 = __expf(v.y - mx),
        e2 = __expf(v.z - mx), e3 = __expf(v.w - mx);
  float sum = e0 + e1 + e2 + e3;
#pragma unroll
  for (int off = 32; off > 0; off >>= 1)
    sum += __shfl_xor(sum, off);
  if (lane == 0) reds[wv] = sum;
  __syncthreads();
  sum = reds[0] + reds[1] + reds[2] + reds[3];
  const float inv = 1.0f / sum;
  w[4 * t + 0] = f2bf(e0 * inv);
  w[4 * t + 1] = f2bf(e1 * inv);
  w[4 * t + 2] = f2bf(e2 * inv);
  w[4 * t + 3] = f2bf(e3 * inv);
}

// ---------------------------------------------------------------------------
// fp32 -> bf16 weight convert (1M elements, 4/thread)
// ---------------------------------------------------------------------------
__global__ __launch_bounds__(256)
void cvt_w(const float* __restrict__ in, unsigned short* __restrict__ out)
{
  const int i = blockIdx.x * 256 + threadIdx.x;
  float4 v = ((const float4*)in)[i];
  ushort4 o;
  o.x = f2bf(v.x); o.y = f2bf(v.y); o.z = f2bf(v.z); o.w = f2bf(v.w);
  ((ushort4*)out)[i] = o;
}

extern "C" void kernel_launch(void* const* d_in, const int* in_sizes, int n_in,
                              void* d_out, int out_size, void* d_ws, size_t ws_size,
                              hipStream_t stream)
{
  const float* shape_map = (const float*)d_in[0];
  const float* img_map   = (const float*)d_in[1];
  const float* wq = (const float*)d_in[2];
  const float* bq = (const float*)d_in[3];
  const float* wk = (const float*)d_in[4];
  const float* bk = (const float*)d_in[5];
  const float* wv = (const float*)d_in[6];
  const float* bv = (const float*)d_in[7];
  const float* wc = (const float*)d_in[8];
  const float* bc = (const float*)d_in[9];
  float* out = (float*)d_out;

  const size_t ELT = 1024 * 1024;           // elements per [1024][1024] matrix
  const size_t MB  = 1024 * 1024;           // bytes
  char* ws = (char*)d_ws;

  // workspace layout: 8MB bf16 weights, then per-batch 10MB slots with reuse:
  //   +0MB: Xt(2) | Yt(2)   -> later S fp32(4)
  //   +4MB: Q(2)            -> later Wsm(2)
  //   +6MB: K2(2)           -> later NVt(2)
  //   +8MB: Vt(2)
  unsigned short* wq_b = (unsigned short*)(ws + 0 * 2 * MB);
  unsigned short* wk_b = (unsigned short*)(ws + 1 * 2 * MB);
  unsigned short* wv_b = (unsigned short*)(ws + 2 * 2 * MB);
  unsigned short* wc_b = (unsigned short*)(ws + 3 * 2 * MB);
  char* slots = ws + 8 * MB;
  const size_t slotBytes = 10 * MB;
  int nslots = (ws_size > 8 * MB + slotBytes)
                   ? (int)((ws_size - 8 * MB) / slotBytes) : 1;
  if (nslots > 32) nslots = 32;
  if (nslots < 1)  nslots = 1;

  cvt_w<<<1024, 256, 0, stream>>>(wq, wq_b);
  cvt_w<<<1024, 256, 0, stream>>>(wk, wk_b);
  cvt_w<<<1024, 256, 0, stream>>>(wv, wv_b);
  cvt_w<<<1024, 256, 0, stream>>>(wc, wc_b);

  const size_t sBf = slotBytes / 2;   // ushort elements per slot
  const size_t sF  = slotBytes / 4;   // float elements per slot

  for (int c0 = 0; c0 < 32; c0 += nslots) {
    const int nb = (32 - c0 < nslots) ? (32 - c0) : nslots;

    unsigned short* Xt  = (unsigned short*)(slots + 0);
    unsigned short* Yt  = (unsigned short*)(slots + 2 * MB);
    float*          Sm  = (float*)(slots + 0);
    unsigned short* Qb  = (unsigned short*)(slots + 4 * MB);
    unsigned short* Kb  = (unsigned short*)(slots + 6 * MB);
    unsigned short* Vt  = (unsigned short*)(slots + 8 * MB);
    unsigned short* Wsm = Qb;   // Q dead after scores
    unsigned short* NVt = Kb;   // K2 dead after scores

    dim3 tgrid(32, 32, nb), tblk(32, 8);
    transpose_cvt<<<tgrid, tblk, 0, stream>>>(shape_map + (size_t)c0 * ELT, Xt, ELT, sBf);
    transpose_cvt<<<tgrid, tblk, 0, stream>>>(img_map   + (size_t)c0 * ELT, Yt, ELT, sBf);

    dim3 ggrid(8, 8, nb);
    // Q[o][s] = tanh(Wq.Xt + bq)
    gemm_bt<0, 1, 1, 0><<<ggrid, 256, 0, stream>>>(
        wq_b, Xt, Qb, bq, nullptr, 1.0f, 0, sBf, sBf, 0);
    // K2[d][s] = tanh(Wk.Yt + bk)
    gemm_bt<0, 1, 1, 0><<<ggrid, 256, 0, stream>>>(
        wk_b, Yt, Kb, bk, nullptr, 1.0f, 0, sBf, sBf, 0);
    // Vt[s][d] = tanh(Yt.Wv + bv)
    gemm_bt<0, 2, 1, 0><<<ggrid, 256, 0, stream>>>(
        Yt, wv_b, Vt, bv, nullptr, 1.0f, sBf, 0, sBf, 0);
    // S[c][d] = Q.K2 / 32   (fp32)
    gemm_bt<1, 0, 0, 0><<<ggrid, 256, 0, stream>>>(
        Qb, Kb, Sm, nullptr, nullptr, 0.03125f, sBf, sBf, sF, 0);
    // softmax rows -> bf16 weights
    softmax_rows<<<dim3(1024, nb), 256, 0, stream>>>(Sm, Wsm, sF, sBf);
    // NVt[s][c] = Vt.Wsm
    gemm_bt<0, 0, 0, 0><<<ggrid, 256, 0, stream>>>(
        Vt, Wsm, NVt, nullptr, nullptr, 1.0f, sBf, sBf, sBf, 0);
    // out[o][s] = Wc.NVt + bc + shape_map   (fp32, final layout)
    gemm_bt<1, 1, 0, 1><<<ggrid, 256, 0, stream>>>(
        wc_b, NVt, out + (size_t)c0 * ELT, bc,
        shape_map + (size_t)c0 * ELT, 1.0f, 0, sBf, ELT, ELT);
  }
}

// Round 2
// 1011.299 us; speedup vs baseline: 1.0087x; 1.0087x over previous
//
#include <hip/hip_runtime.h>

// AttentionFusion on MI355X (gfx950). B=32, C=1024, HW=1024.
// All GEMMs 1024^3, bf16 MFMA fp32-acc, BM=BN=128, BK=64, 4 waves.
// LDS bank-conflict-free via XOR swizzle of the staged column-group.

typedef __bf16 bf16x8 __attribute__((ext_vector_type(8)));
typedef float floatx4 __attribute__((ext_vector_type(4)));

__device__ __forceinline__ unsigned short f2bf(float f) {
  union { float f; unsigned int u; } c; c.f = f;
  unsigned int u = c.u;
  u += 0x7fffu + ((u >> 16) & 1u);   // RNE to bf16
  return (unsigned short)(u >> 16);
}

__device__ __forceinline__ float tanh_fast(float x) {
  x = fminf(15.0f, fmaxf(-15.0f, x));
  float t = __expf(2.0f * x);
  return (t - 1.0f) / (t + 1.0f);
}

// ---------------------------------------------------------------------------
// Shared GEMM core: acc[m][n] += sum_k A[m][k]*B[n][k], K=1024, BK=64.
// LDS tile layout: [row][64] ushorts, but column-group cg (8 elems = 16B) is
// stored at physical slot cg ^ (row&7).  Staging lane l of chunk q writes
// LDS byte q*1024 + l*16 == logical (row = q*8 + l/8, cg_phys = l&7), so the
// lane fetches global cg_log = (l&7) ^ (l>>3).  Readers XOR the same term.
// Bank check: ds_read_b128 addr/4 % 32 = 4*((ks*4+quad) ^ (lm&7)) -> each
// 32-lane phase covers all 8 4-bank groups evenly (conflict-free).
// ---------------------------------------------------------------------------
__device__ __forceinline__ void gemm_core(
    const unsigned short* __restrict__ Ab,
    const unsigned short* __restrict__ Bb,
    int m0, int n0,
    unsigned short* lA, unsigned short* lB,
    floatx4 acc[4][4])
{
  constexpr int K = 1024;
  const int tid  = threadIdx.x;
  const int w    = tid >> 6;
  const int lane = tid & 63;
  const int quad = lane >> 4;
  const int lm   = lane & 15;
  const int wm   = (w >> 1) * 64;
  const int wn   = (w & 1) * 64;
  const int xr   = lm & 7;

  // staging: lane covers 16B; chunk = 8 rows x 128B
  const int srow = lane >> 3;                 // 0..7 within chunk
  const int sg   = (lane & 7) ^ srow;         // swizzled source col-group
  const unsigned short* gA0 = Ab + (size_t)(m0 + srow) * K + sg * 8;
  const unsigned short* gB0 = Bb + (size_t)(n0 + srow) * K + sg * 8;

  for (int k0 = 0; k0 < K; k0 += 64) {
#pragma unroll
    for (int i = 0; i < 4; ++i) {
      const int q = w * 4 + i;                // 16 chunks per tile, 4/wave
      __builtin_amdgcn_global_load_lds(
          (__attribute__((address_space(1))) void*)(gA0 + (size_t)q * 8 * K + k0),
          (__attribute__((address_space(3))) void*)(lA + q * 512), 16, 0, 0);
      __builtin_amdgcn_global_load_lds(
          (__attribute__((address_space(1))) void*)(gB0 + (size_t)q * 8 * K + k0),
          (__attribute__((address_space(3))) void*)(lB + q * 512), 16, 0, 0);
    }
    __syncthreads();   // drains vmcnt(0) before barrier

#pragma unroll
    for (int ks = 0; ks < 2; ++ks) {
      bf16x8 af[4], bfv[4];
#pragma unroll
      for (int i = 0; i < 4; ++i) {
        const int row = wm + 16 * i + lm;
        af[i] = *(const bf16x8*)(lA + row * 64 + (((ks * 4 + quad) ^ xr) * 8));
      }
#pragma unroll
      for (int j = 0; j < 4; ++j) {
        const int row = wn + 16 * j + lm;
        bfv[j] = *(const bf16x8*)(lB + row * 64 + (((ks * 4 + quad) ^ xr) * 8));
      }
#pragma unroll
      for (int i = 0; i < 4; ++i)
#pragma unroll
        for (int j = 0; j < 4; ++j)
          acc[i][j] = __builtin_amdgcn_mfma_f32_16x16x32_bf16(
              af[i], bfv[j], acc[i][j], 0, 0, 0);
    }
    __syncthreads();
  }
}

// ---------------------------------------------------------------------------
// Generic epilogue GEMM (templated): C = epi(scale * A.B^T)
// ---------------------------------------------------------------------------
template<int OUT_F32, int BIAS_MODE /*0 none,1 m,2 n*/, int TANH_ON, int RESID_ON>
__global__ __launch_bounds__(256, 2)
void gemm_bt(const unsigned short* __restrict__ A,
             const unsigned short* __restrict__ B,
             void* __restrict__ Cv,
             const float* __restrict__ bias,
             const float* __restrict__ resid,
             float scale,
             size_t sA, size_t sB, size_t sC, size_t sR)
{
  __shared__ unsigned short lA[128 * 64];
  __shared__ unsigned short lB[128 * 64];
  const int m0 = blockIdx.y * 128, n0 = blockIdx.x * 128;
  const int lane = threadIdx.x & 63, w = threadIdx.x >> 6;
  const int quad = lane >> 4, lm = lane & 15;
  const int wm = (w >> 1) * 64, wn = (w & 1) * 64;

  floatx4 acc[4][4];
#pragma unroll
  for (int i = 0; i < 4; ++i)
#pragma unroll
    for (int j = 0; j < 4; ++j) acc[i][j] = (floatx4)(0.0f);

  gemm_core(A + blockIdx.z * sA, B + blockIdx.z * sB, m0, n0, lA, lB, acc);

  float* Cf = (float*)Cv + blockIdx.z * sC;
  unsigned short* Cb = (unsigned short*)Cv + blockIdx.z * sC;
  const float* rp = RESID_ON ? (resid + blockIdx.z * sR) : (const float*)0;

  // C/D mapping (verified): n = lane&15, m = quad*4 + reg
#pragma unroll
  for (int i = 0; i < 4; ++i) {
    const int mbase = m0 + wm + 16 * i + quad * 4;
#pragma unroll
    for (int j = 0; j < 4; ++j) {
      const int n = n0 + wn + 16 * j + lm;
#pragma unroll
      for (int r = 0; r < 4; ++r) {
        const int m = mbase + r;
        float val = acc[i][j][r] * scale;
        if (BIAS_MODE == 1) val += bias[m];
        if (BIAS_MODE == 2) val += bias[n];
        if (TANH_ON) val = tanh_fast(val);
        if (RESID_ON) val += rp[(size_t)m * 1024 + n];
        if (OUT_F32) Cf[(size_t)m * 1024 + n] = val;
        else         Cb[(size_t)m * 1024 + n] = f2bf(val);
      }
    }
  }
}

// ---------------------------------------------------------------------------
// Fused Q/K/V GEMM: z in [0,3*nb) selects op + batch.  All tanh, bf16 out.
// ---------------------------------------------------------------------------
__global__ __launch_bounds__(256, 2)
void qkv_gemm(const unsigned short* __restrict__ wqb,
              const unsigned short* __restrict__ wkb,
              const unsigned short* __restrict__ wvb,
              const unsigned short* __restrict__ Xt,
              const unsigned short* __restrict__ Yt,
              unsigned short* __restrict__ Qb,
              unsigned short* __restrict__ Kb,
              unsigned short* __restrict__ Vt,
              const float* __restrict__ bq,
              const float* __restrict__ bk,
              const float* __restrict__ bv,
              size_t sBf, int nb)
{
  __shared__ unsigned short lA[128 * 64];
  __shared__ unsigned short lB[128 * 64];
  const int z = blockIdx.z;
  int op, b;
  if (z >= 2 * nb)      { op = 2; b = z - 2 * nb; }
  else if (z >= nb)     { op = 1; b = z - nb; }
  else                  { op = 0; b = z; }

  const unsigned short *A, *B;
  unsigned short* C;
  const float* bias;
  int biasM;   // 1 = along m, 0 = along n
  if (op == 0)      { A = wqb;            B = Xt + b * sBf; C = Qb + b * sBf; bias = bq; biasM = 1; }
  else if (op == 1) { A = wkb;            B = Yt + b * sBf; C = Kb + b * sBf; bias = bk; biasM = 1; }
  else              { A = Yt + b * sBf;   B = wvb;          C = Vt + b * sBf; bias = bv; biasM = 0; }

  const int m0 = blockIdx.y * 128, n0 = blockIdx.x * 128;
  const int lane = threadIdx.x & 63, w = threadIdx.x >> 6;
  const int quad = lane >> 4, lm = lane & 15;
  const int wm = (w >> 1) * 64, wn = (w & 1) * 64;

  floatx4 acc[4][4];
#pragma unroll
  for (int i = 0; i < 4; ++i)
#pragma unroll
    for (int j = 0; j < 4; ++j) acc[i][j] = (floatx4)(0.0f);

  gemm_core(A, B, m0, n0, lA, lB, acc);

#pragma unroll
  for (int i = 0; i < 4; ++i) {
    const int mbase = m0 + wm + 16 * i + quad * 4;
#pragma unroll
    for (int j = 0; j < 4; ++j) {
      const int n = n0 + wn + 16 * j + lm;
      const float bn = biasM ? 0.0f : bias[n];
#pragma unroll
      for (int r = 0; r < 4; ++r) {
        const int m = mbase + r;
        float val = acc[i][j][r] + (biasM ? bias[m] : bn);
        val = tanh_fast(val);
        C[(size_t)m * 1024 + n] = f2bf(val);
      }
    }
  }
}

// ---------------------------------------------------------------------------
// Dual transpose 1024x1024 fp32 -> bf16: z<nb: in0->out0, else in1->out1
// ---------------------------------------------------------------------------
__global__ __launch_bounds__(256)
void transpose2(const float* __restrict__ in0, const float* __restrict__ in1,
                unsigned short* __restrict__ out0, unsigned short* __restrict__ out1,
                size_t sIn, size_t sOut, int nb)
{
  __shared__ float tile[32][33];
  const int z = blockIdx.z;
  const float* in;
  unsigned short* out;
  if (z < nb) { in = in0 + (size_t)z * sIn;        out = out0 + (size_t)z * sOut; }
  else        { in = in1 + (size_t)(z - nb) * sIn; out = out1 + (size_t)(z - nb) * sOut; }

  const int x  = blockIdx.x * 32 + threadIdx.x;
  const int y0 = blockIdx.y * 32;
#pragma unroll
  for (int k = 0; k < 32; k += 8)
    tile[threadIdx.y + k][threadIdx.x] =
        in[(size_t)(y0 + threadIdx.y + k) * 1024 + x];
  __syncthreads();
  const int xo  = blockIdx.y * 32 + threadIdx.x;
  const int yo0 = blockIdx.x * 32;
#pragma unroll
  for (int k = 0; k < 32; k += 8)
    out[(size_t)(yo0 + threadIdx.y + k) * 1024 + xo] =
        f2bf(tile[threadIdx.x][threadIdx.y + k]);
}

// ---------------------------------------------------------------------------
// Row softmax: 1024 fp32 -> 1024 bf16, one block per row
// ---------------------------------------------------------------------------
__global__ __launch_bounds__(256)
void softmax_rows(const float* __restrict__ S, unsigned short* __restrict__ W,
                  size_t sS, size_t sW)
{
  const float* s = S + blockIdx.y * sS + (size_t)blockIdx.x * 1024;
  unsigned short* w = W + blockIdx.y * sW + (size_t)blockIdx.x * 1024;
  const int t = threadIdx.x;
  float4 v = ((const float4*)s)[t];
  float mx = fmaxf(fmaxf(v.x, v.y), fmaxf(v.z, v.w));
#pragma unroll
  for (int off = 32; off > 0; off >>= 1)
    mx = fmaxf(mx, __shfl_xor(mx, off));
  __shared__ float redm[4], reds[4];
  const int lane = t & 63, wv = t >> 6;
  if (lane == 0) redm[wv] = mx;
  __syncthreads();
  mx = fmaxf(fmaxf(redm[0], redm[1]), fmaxf(redm[2], redm[3]));
  float e0 = __expf(v.x - mx), e1 = __expf(v.y - mx),
        e2 = __expf(v.z - mx), e3 = __expf(v.w - mx);
  float sum = e0 + e1 + e2 + e3;
#pragma unroll
  for (int off = 32; off > 0; off >>= 1)
    sum += __shfl_xor(sum, off);
  if (lane == 0) reds[wv] = sum;
  __syncthreads();
  sum = reds[0] + reds[1] + reds[2] + reds[3];
  const float inv = 1.0f / sum;
  w[4 * t + 0] = f2bf(e0 * inv);
  w[4 * t + 1] = f2bf(e1 * inv);
  w[4 * t + 2] = f2bf(e2 * inv);
  w[4 * t + 3] = f2bf(e3 * inv);
}

// ---------------------------------------------------------------------------
// Convert all four 1024x1024 fp32 weights -> bf16 in one dispatch (y=op)
// ---------------------------------------------------------------------------
__global__ __launch_bounds__(256)
void cvt_all(const float* __restrict__ s0, const float* __restrict__ s1,
             const float* __restrict__ s2, const float* __restrict__ s3,
             unsigned short* __restrict__ d0, unsigned short* __restrict__ d1,
             unsigned short* __restrict__ d2, unsigned short* __restrict__ d3)
{
  const float* in; unsigned short* out;
  switch (blockIdx.y) {
    case 0: in = s0; out = d0; break;
    case 1: in = s1; out = d1; break;
    case 2: in = s2; out = d2; break;
    default: in = s3; out = d3; break;
  }
  const int i = blockIdx.x * 256 + threadIdx.x;
  float4 v = ((const float4*)in)[i];
  ushort4 o;
  o.x = f2bf(v.x); o.y = f2bf(v.y); o.z = f2bf(v.z); o.w = f2bf(v.w);
  ((ushort4*)out)[i] = o;
}

extern "C" void kernel_launch(void* const* d_in, const int* in_sizes, int n_in,
                              void* d_out, int out_size, void* d_ws, size_t ws_size,
                              hipStream_t stream)
{
  const float* shape_map = (const float*)d_in[0];
  const float* img_map   = (const float*)d_in[1];
  const float* wq = (const float*)d_in[2];
  const float* bq = (const float*)d_in[3];
  const float* wk = (const float*)d_in[4];
  const float* bk = (const float*)d_in[5];
  const float* wv = (const float*)d_in[6];
  const float* bv = (const float*)d_in[7];
  const float* wc = (const float*)d_in[8];
  const float* bc = (const float*)d_in[9];
  float* out = (float*)d_out;

  const size_t ELT = 1024 * 1024;
  const size_t MB  = 1024 * 1024;
  char* ws = (char*)d_ws;

  // 8MB bf16 weights, then per-batch 10MB slots with buffer reuse:
  //   +0MB: Xt(2)|Yt(2) -> later S fp32(4); +4MB Q->Wsm; +6MB K2->NVt; +8MB Vt
  unsigned short* wq_b = (unsigned short*)(ws + 0 * 2 * MB);
  unsigned short* wk_b = (unsigned short*)(ws + 1 * 2 * MB);
  unsigned short* wv_b = (unsigned short*)(ws + 2 * 2 * MB);
  unsigned short* wc_b = (unsigned short*)(ws + 3 * 2 * MB);
  char* slots = ws + 8 * MB;
  const size_t slotBytes = 10 * MB;
  int nslots = (ws_size > 8 * MB + slotBytes)
                   ? (int)((ws_size - 8 * MB) / slotBytes) : 1;
  if (nslots > 32) nslots = 32;
  if (nslots < 1)  nslots = 1;

  cvt_all<<<dim3(1024, 4), 256, 0, stream>>>(wq, wk, wv, wc,
                                             wq_b, wk_b, wv_b, wc_b);

  const size_t sBf = slotBytes / 2;
  const size_t sF  = slotBytes / 4;

  for (int c0 = 0; c0 < 32; c0 += nslots) {
    const int nb = (32 - c0 < nslots) ? (32 - c0) : nslots;

    unsigned short* Xt  = (unsigned short*)(slots + 0);
    unsigned short* Yt  = (unsigned short*)(slots + 2 * MB);
    float*          Sm  = (float*)(slots + 0);
    unsigned short* Qb  = (unsigned short*)(slots + 4 * MB);
    unsigned short* Kb  = (unsigned short*)(slots + 6 * MB);
    unsigned short* Vt  = (unsigned short*)(slots + 8 * MB);
    unsigned short* Wsm = Qb;   // Q dead after scores
    unsigned short* NVt = Kb;   // K2 dead after scores

    transpose2<<<dim3(32, 32, 2 * nb), dim3(32, 8), 0, stream>>>(
        shape_map + (size_t)c0 * ELT, img_map + (size_t)c0 * ELT,
        Xt, Yt, ELT, sBf, nb);

    // Q[o][s], K2[d][s], Vt[s][d] in one dispatch
    qkv_gemm<<<dim3(8, 8, 3 * nb), 256, 0, stream>>>(
        wq_b, wk_b, wv_b, Xt, Yt, Qb, Kb, Vt, bq, bk, bv, sBf, nb);

    // S[c][d] = Q.K2 / 32   (fp32)
    gemm_bt<1, 0, 0, 0><<<dim3(8, 8, nb), 256, 0, stream>>>(
        Qb, Kb, Sm, nullptr, nullptr, 0.03125f, sBf, sBf, sF, 0);

    softmax_rows<<<dim3(1024, nb), 256, 0, stream>>>(Sm, Wsm, sF, sBf);

    // NVt[s][c] = Vt.Wsm
    gemm_bt<0, 0, 0, 0><<<dim3(8, 8, nb), 256, 0, stream>>>(
        Vt, Wsm, NVt, nullptr, nullptr, 1.0f, sBf, sBf, sBf, 0);

    // out[o][s] = Wc.NVt + bc + shape_map
    gemm_bt<1, 1, 0, 1><<<dim3(8, 8, nb), 256, 0, stream>>>(
        wc_b, NVt, out + (size_t)c0 * ELT, bc,
        shape_map + (size_t)c0 * ELT, 1.0f, 0, sBf, ELT, ELT);
  }
}